// Round 2
// baseline (2228.391 us; speedup 1.0000x reference)
//
#include <hip/hip_runtime.h>
#include <hip/hip_bf16.h>

typedef unsigned short u16;
typedef unsigned int u32;
typedef __attribute__((ext_vector_type(8))) short short8;
typedef __attribute__((ext_vector_type(4))) float f32x4;

#define LDSP 40   // LDS row pitch (elements); 2-way bank conflicts only (free)

__device__ __forceinline__ u16 f2b(float f) {
  u32 u = __builtin_bit_cast(u32, f);
  u = (u + 0x7fffu + ((u >> 16) & 1u)) >> 16;   // RNE
  return (u16)u;
}
__device__ __forceinline__ float b2f(u16 s) {
  return __builtin_bit_cast(float, (u32)s << 16);
}

// ---------------------------------------------------------------------------
// GEMM: C[M][N] (+)= A[M][K] * Bt[N][K]^T, bf16 in, f32 accum. 128x128 tile,
// 4 waves of 64x64, mfma_f32_16x16x32_bf16.
// EPI: 0=store f32, 1=relu->bf16, 2=strict-lower mask (gm>gn)->bf16,
//      3=atomicAdd f32 (split-K), 4=relu*aux(bf16)->bf16
// grid.z = nsplits (single batch; per-head base pointers computed on host)
// ---------------------------------------------------------------------------
template<int EPI>
__global__ __launch_bounds__(256, 2) void gemm_bt(
    const u16* __restrict__ A, const u16* __restrict__ B, void* __restrict__ C,
    const u16* __restrict__ aux, int K, int lda, int ldb, int ldc, int aux_ld,
    int nsplits)
{
  int bn = blockIdx.x, bm = blockIdx.y;
  int sp = blockIdx.z;

  if (EPI == 2 && bn > bm) {           // tile entirely above diagonal: zero-fill
    u16* Cb = (u16*)C;
    for (int i = threadIdx.x; i < 128 * 128 / 8; i += 256) {
      int r = i >> 4, c8 = (i & 15) << 3;
      *(uint4*)(&Cb[(long)(bm * 128 + r) * ldc + bn * 128 + c8]) = make_uint4(0u, 0u, 0u, 0u);
    }
    return;
  }

  __shared__ __align__(16) u16 As[128 * LDSP];
  __shared__ __align__(16) u16 Bs[128 * LDSP];

  int tid = threadIdx.x;
  int Klen = K / nsplits, kb = sp * Klen;

  // staging: each thread stages 2x16B of A and 2x16B of B per K-step
  int r0 = tid >> 2;             // 0..63
  int kc = (tid & 3) << 3;       // 0,8,16,24
  const u16* ag0 = A + ((long)bm * 128 + r0) * lda + kb + kc;
  const u16* ag1 = ag0 + (long)64 * lda;
  const u16* bg0 = B + ((long)bn * 128 + r0) * ldb + kb + kc;
  const u16* bg1 = bg0 + (long)64 * ldb;
  u16* as0 = &As[r0 * LDSP + kc]; u16* as1 = as0 + 64 * LDSP;
  u16* bs0 = &Bs[r0 * LDSP + kc]; u16* bs1 = bs0 + 64 * LDSP;

  int wid = tid >> 6, lane = tid & 63;
  int wm = (wid >> 1) << 6, wn = (wid & 1) << 6;
  int lane15 = lane & 15, quad = lane >> 4;

  f32x4 acc[4][4];
#pragma unroll
  for (int i = 0; i < 4; i++)
#pragma unroll
    for (int j = 0; j < 4; j++) { f32x4 z = {0.f, 0.f, 0.f, 0.f}; acc[i][j] = z; }

  // A-frag: A[m=lane&15][k=quad*8+j]; B-frag mirrors with n=lane&15
  const u16* ar = &As[(wm + lane15) * LDSP + quad * 8];
  const u16* br = &Bs[(wn + lane15) * LDSP + quad * 8];

  for (int k = 0; k < Klen; k += 32) {
    uint4 va0 = *(const uint4*)(ag0 + k);
    uint4 va1 = *(const uint4*)(ag1 + k);
    uint4 vb0 = *(const uint4*)(bg0 + k);
    uint4 vb1 = *(const uint4*)(bg1 + k);
    __syncthreads();
    *(uint4*)as0 = va0; *(uint4*)as1 = va1;
    *(uint4*)bs0 = vb0; *(uint4*)bs1 = vb1;
    __syncthreads();
    short8 af[4], bfr[4];
#pragma unroll
    for (int mt = 0; mt < 4; mt++) af[mt] = *(const short8*)(ar + mt * 16 * LDSP);
#pragma unroll
    for (int nt = 0; nt < 4; nt++) bfr[nt] = *(const short8*)(br + nt * 16 * LDSP);
#pragma unroll
    for (int mt = 0; mt < 4; mt++)
#pragma unroll
      for (int nt = 0; nt < 4; nt++)
        acc[mt][nt] = __builtin_amdgcn_mfma_f32_16x16x32_bf16(af[mt], bfr[nt], acc[mt][nt], 0, 0, 0);
  }

  // epilogue: C/D layout col=lane&15, row=quad*4+r (verified m89/m91)
#pragma unroll
  for (int mt = 0; mt < 4; mt++)
#pragma unroll
    for (int nt = 0; nt < 4; nt++)
#pragma unroll
      for (int r = 0; r < 4; r++) {
        int gm = bm * 128 + wm + mt * 16 + quad * 4 + r;
        int gn = bn * 128 + wn + nt * 16 + lane15;
        float v = acc[mt][nt][r];
        long ci = (long)gm * ldc + gn;
        if (EPI == 0) {
          ((float*)C)[ci] = v;
        } else if (EPI == 1) {
          ((u16*)C)[ci] = f2b(fmaxf(v, 0.f));
        } else if (EPI == 2) {
          ((u16*)C)[ci] = f2b(gm > gn ? v : 0.f);
        } else if (EPI == 3) {
          atomicAdd(&((float*)C)[ci], v);
        } else if (EPI == 4) {
          float xs = b2f(aux[(long)gm * aux_ld + gn]);
          ((u16*)C)[ci] = f2b(fmaxf(v, 0.f) * xs);
        }
      }
}

// ---------------------------------------------------------------------------
// transpose + f32->bf16: dst[c][r] = src[r][c]; grid (C/32, R/32, batch)
// ---------------------------------------------------------------------------
__global__ __launch_bounds__(256) void trans_f32_bf16(
    const float* __restrict__ src, u16* __restrict__ dst, int R, int C)
{
  __shared__ float tile[32][33];
  long off = (long)blockIdx.z * R * C;
  const float* s = src + off;
  u16* d = dst + off;
  int lx = threadIdx.x & 31, ly = threadIdx.x >> 5;   // ly 0..7
  int c = blockIdx.x * 32 + lx;
#pragma unroll
  for (int p = 0; p < 32; p += 8)
    tile[ly + p][lx] = s[(long)(blockIdx.y * 32 + ly + p) * C + c];
  __syncthreads();
  int rr = blockIdx.y * 32 + lx;
#pragma unroll
  for (int p = 0; p < 32; p += 8)
    d[(long)(blockIdx.x * 32 + ly + p) * R + rr] = f2b(tile[lx][ly + p]);
}

// ---------------------------------------------------------------------------
__device__ __forceinline__ float block_sum(float v, float* red) {
#pragma unroll
  for (int o = 32; o > 0; o >>= 1) v += __shfl_down(v, o, 64);
  int lane = threadIdx.x & 63, wid = threadIdx.x >> 6;
  if (lane == 0) red[wid] = v;
  __syncthreads();
  float r = red[0] + red[1] + red[2] + red[3];
  __syncthreads();
  return r;
}

// x = ln(embed[idx]); writes f32 master, bf16, bf16-transposed
__global__ __launch_bounds__(256) void embed_ln(
    const int* __restrict__ idx, const float* __restrict__ embed,
    float* __restrict__ x, u16* __restrict__ xb, u16* __restrict__ xT, int T)
{
  __shared__ float red[4];
  int t = blockIdx.x, d = threadIdx.x;
  float v = embed[(long)idx[t] * 256 + d];
  float mu = block_sum(v, red) * (1.f / 256.f);
  float c = v - mu;
  float var = block_sum(c * c, red) * (1.f / 256.f);
  float o = c * rsqrtf(var + 1e-5f);
  x[(long)t * 256 + d] = o;
  xb[(long)t * 256 + d] = f2b(o);
  xT[(long)d * T + t] = f2b(o);
}

// rope over one head's [T][N] buffer: out = v*cos + rot(v)*sin
// freqs: even index n -> q=n; f = 2^(-q/512)/(2pi); phase = frac(t*f)*2pi
__global__ __launch_bounds__(256) void rope_kernel(
    const u16* __restrict__ in, u16* __restrict__ out)
{
  long i = ((long)blockIdx.x * 256 + threadIdx.x) * 8;
  int n0 = (int)(i & 8191);
  int t = (int)(i >> 13);
  uint4 raw = *(const uint4*)(in + i);
  u32 rw[4] = {raw.x, raw.y, raw.z, raw.w};
  u32 ro[4];
#pragma unroll
  for (int p = 0; p < 4; p++) {
    float e = b2f((u16)(rw[p] & 0xffffu));
    float o = b2f((u16)(rw[p] >> 16));
    int n = n0 + 2 * p;                       // even -> q = n
    float f = exp2f((float)(-n) * (1.0f / 512.0f)) * 0.15915494f;
    float ph = (float)t * f;
    ph -= floorf(ph);
    float sn, cs;
    __sincosf(ph * 6.2831853f, &sn, &cs);
    float oe = e * cs - o * sn;
    float oo = o * cs + e * sn;
    ro[p] = (u32)f2b(oe) | ((u32)f2b(oo) << 16);
  }
  *(uint4*)(out + i) = make_uint4(ro[0], ro[1], ro[2], ro[3]);
}

// per-row layernorm f32 -> bf16 (yKV)
__global__ __launch_bounds__(256) void row_ln(
    const float* __restrict__ in, u16* __restrict__ out)
{
  __shared__ float red[4];
  long row = blockIdx.x;
  int d = threadIdx.x;
  float v = in[row * 256 + d];
  float mu = block_sum(v, red) * (1.f / 256.f);
  float c = v - mu;
  float var = block_sum(c * c, red) * (1.f / 256.f);
  out[row * 256 + d] = f2b(c * rsqrtf(var + 1e-5f));
}

// x = ln(x + ln(yMLP)); updates f32 master, bf16, bf16-transposed
__global__ __launch_bounds__(256) void resid_ln(
    const float* __restrict__ yMLP, float* __restrict__ x,
    u16* __restrict__ xb, u16* __restrict__ xT, int T)
{
  __shared__ float red[4];
  int t = blockIdx.x, d = threadIdx.x;
  float y = yMLP[(long)t * 256 + d];
  float mu1 = block_sum(y, red) * (1.f / 256.f);
  float c1 = y - mu1;
  float var1 = block_sum(c1 * c1, red) * (1.f / 256.f);
  float l1 = c1 * rsqrtf(var1 + 1e-5f);
  float v = x[(long)t * 256 + d] + l1;
  float mu2 = block_sum(v, red) * (1.f / 256.f);
  float c2 = v - mu2;
  float var2 = block_sum(c2 * c2, red) * (1.f / 256.f);
  float o = c2 * rsqrtf(var2 + 1e-5f);
  x[(long)t * 256 + d] = o;
  xb[(long)t * 256 + d] = f2b(o);
  xT[(long)d * T + t] = f2b(o);
}

// ---------------------------------------------------------------------------
extern "C" void kernel_launch(void* const* d_in, const int* in_sizes, int n_in,
                              void* d_out, int out_size, void* d_ws, size_t ws_size,
                              hipStream_t stream) {
  const int*   idx       = (const int*)d_in[0];
  const float* embed     = (const float*)d_in[1];
  const float* encoder   = (const float*)d_in[2];
  const float* encoder_v = (const float*)d_in[3];
  const float* decoder   = (const float*)d_in[4];
  const float* lm_head   = (const float*)d_in[5];
  const int T = in_sizes[0];                 // 2048
  const int D = 256, NH = 4, Nn = 8192, V = 256;

  char* ws = (char*)d_ws;
  size_t off = 0;
  auto alloc = [&](size_t bytes) -> void* {
    void* p = ws + off; off += (bytes + 255) & ~(size_t)255; return p;
  };
  // per-head processing keeps the footprint ~129 MB (fits 256 MB workspace)
  float* x_f32   = (float*)alloc((size_t)T * D * 4);          //  2 MB
  float* yMLP    = (float*)alloc((size_t)T * D * 4);          //  2 MB
  float* yKV_f32 = (float*)alloc((size_t)T * D * 4);          //  2 MB (per-head)
  u16* x_b    = (u16*)alloc((size_t)T * D * 2);               //  1 MB
  u16* xT     = (u16*)alloc((size_t)T * D * 2);               //  1 MB
  u16* yKV_b  = (u16*)alloc((size_t)T * D * 2);               //  1 MB (per-head)
  u16* lmT    = (u16*)alloc((size_t)D * V * 2);               //  .125 MB
  u16* encT   = (u16*)alloc((size_t)NH * Nn * D * 2);         // 16 MB
  u16* encvT  = (u16*)alloc((size_t)NH * Nn * D * 2);         // 16 MB
  u16* decT   = (u16*)alloc((size_t)D * NH * Nn * 2);         // 16 MB
  u16* scores = (u16*)alloc((size_t)T * T * 2);               //  8 MB (per-head)
  u16* xsp    = (u16*)alloc((size_t)T * Nn * 2);              // 32 MB (per-head)
  u16* qrxy   = (u16*)alloc((size_t)T * Nn * 2);              // 32 MB (per-head; QR then xy)
  if (off > ws_size) return;

  // one-time weight prep: transpose to K-major bf16
  trans_f32_bf16<<<dim3(Nn / 32, D / 32, NH), 256, 0, stream>>>(encoder, encT, D, Nn);
  trans_f32_bf16<<<dim3(Nn / 32, D / 32, NH), 256, 0, stream>>>(encoder_v, encvT, D, Nn);
  trans_f32_bf16<<<dim3(D / 32, (NH * Nn) / 32, 1), 256, 0, stream>>>(decoder, decT, NH * Nn, D);
  trans_f32_bf16<<<dim3(V / 32, D / 32, 1), 256, 0, stream>>>(lm_head, lmT, D, V);

  embed_ln<<<T, 256, 0, stream>>>(idx, embed, x_f32, x_b, xT, T);

  for (int l = 0; l < 2; l++) {
    hipMemsetAsync(yMLP, 0, (size_t)T * D * 4, stream);
    for (int h = 0; h < NH; h++) {
      const u16* encT_h  = encT  + (size_t)h * Nn * D;
      const u16* encvT_h = encvT + (size_t)h * Nn * D;
      const u16* decT_h  = decT  + (size_t)h * Nn;     // column offset in [D][NH*Nn]

      // x_sparse_h = relu(x @ encoder[h])           [T][Nn]
      gemm_bt<1><<<dim3(Nn / 128, T / 128, 1), 256, 0, stream>>>(
          x_b, encT_h, xsp, nullptr, D, D, D, Nn, 0, 1);
      // QR_h = rope(x_sparse_h)
      rope_kernel<<<(T * (Nn / 8)) / 256, 256, 0, stream>>>(xsp, qrxy);
      // scores_h = (QR @ QR^T) * strict_lower_mask  [T][T] bf16
      gemm_bt<2><<<dim3(T / 128, T / 128, 1), 256, 0, stream>>>(
          qrxy, qrxy, scores, nullptr, Nn, Nn, Nn, T, 0, 1);
      // yKV_h = scores_h @ x   (split-K=8, atomic f32)
      hipMemsetAsync(yKV_f32, 0, (size_t)T * D * 4, stream);
      gemm_bt<3><<<dim3(D / 128, T / 128, 8), 256, 0, stream>>>(
          scores, xT, yKV_f32, nullptr, T, T, T, D, 0, 8);
      // yKV_h = ln(yKV_h)
      row_ln<<<T, 256, 0, stream>>>(yKV_f32, yKV_b);
      // xy_h = relu(yKV_h @ encoder_v[h]) * x_sparse_h   (into QR buffer)
      gemm_bt<4><<<dim3(Nn / 128, T / 128, 1), 256, 0, stream>>>(
          yKV_b, encvT_h, qrxy, xsp, D, D, D, Nn, Nn, 1);
      // yMLP += xy_h @ decoder[h]   (split-K=8, atomic f32)
      gemm_bt<3><<<dim3(D / 128, T / 128, 8), 256, 0, stream>>>(
          qrxy, decT_h, yMLP, nullptr, Nn, Nn, NH * Nn, D, 0, 8);
    }
    // x = ln(x + ln(yMLP))
    resid_ln<<<T, 256, 0, stream>>>(yMLP, x_f32, x_b, xT, T);
  }

  // logits = x @ lm_head  (f32 out)
  gemm_bt<0><<<dim3(V / 128, T / 128, 1), 256, 0, stream>>>(
      x_b, lmT, d_out, nullptr, D, D, D, V, 0, 1);
}

// Round 3
// 1428.511 us; speedup vs baseline: 1.5599x; 1.5599x over previous
//
#include <hip/hip_runtime.h>
#include <hip/hip_bf16.h>
#include <math.h>

typedef unsigned short u16;
typedef unsigned int u32;
typedef __attribute__((ext_vector_type(8))) short short8;
typedef __attribute__((ext_vector_type(4))) float f32x4;

__device__ __forceinline__ u16 f2b(float f) {
  u32 u = __builtin_bit_cast(u32, f);
  u = (u + 0x7fffu + ((u >> 16) & 1u)) >> 16;   // RNE
  return (u16)u;
}
__device__ __forceinline__ float b2f(u16 s) {
  return __builtin_bit_cast(float, (u32)s << 16);
}

// async global->LDS, 16B per lane; LDS dest = wave-uniform base + lane*16
__device__ __forceinline__ void ld_g2l(const u16* g, u16* l) {
  __builtin_amdgcn_global_load_lds(
      (const __attribute__((address_space(1))) unsigned int*)g,
      (__attribute__((address_space(3))) unsigned int*)l, 16, 0, 0);
}

// ---------------------------------------------------------------------------
// Core 128x128 tile GEMM: acc += A[128 rows][K] * B[128 rows][K]^T.
// BK=32, LDS pitch 32 (no pad: whole-wave b128 frag reads are contiguous
// 1024B -> conflict-free, and global_load_lds needs lane-order layout).
// 4 waves of 64x64, mfma_f32_16x16x32_bf16 (frag: m/n=lane&15, k=quad*8+j).
// ---------------------------------------------------------------------------
__device__ __forceinline__ void gemm_core(
    const u16* __restrict__ A, const u16* __restrict__ B,
    int lda, int ldb, int Klen, int kb, int bm, int bn,
    u16* __restrict__ As, u16* __restrict__ Bs, f32x4 (&acc)[4][4])
{
  int tid = threadIdx.x;
  int w = tid >> 6, lane = tid & 63;
  int srow = (w << 4) + (lane >> 2);       // 0..63
  int scol = (lane & 3) << 3;              // element 0,8,16,24
  const u16* ga0 = A + (long)(bm * 128 + srow) * lda + kb + scol;
  const u16* ga1 = ga0 + (long)64 * lda;
  const u16* gb0 = B + (long)(bn * 128 + srow) * ldb + kb + scol;
  const u16* gb1 = gb0 + (long)64 * ldb;
  u16* la0 = As + (w << 9);  u16* la1 = la0 + 2048;   // rows 16w.. / 64+16w..
  u16* lb0 = Bs + (w << 9);  u16* lb1 = lb0 + 2048;

  int wm = (w >> 1) << 6, wn = (w & 1) << 6;
  int lane15 = lane & 15, quad = lane >> 4;
  const u16* ar = As + (wm + lane15) * 32 + quad * 8;
  const u16* br = Bs + (wn + lane15) * 32 + quad * 8;

#pragma unroll
  for (int i = 0; i < 4; i++)
#pragma unroll
    for (int j = 0; j < 4; j++) { f32x4 z = {0.f, 0.f, 0.f, 0.f}; acc[i][j] = z; }

  for (int k = 0; k < Klen; k += 32) {
    ld_g2l(ga0 + k, la0);
    ld_g2l(ga1 + k, la1);
    ld_g2l(gb0 + k, lb0);
    ld_g2l(gb1 + k, lb1);
    __syncthreads();                        // drains vmcnt -> staging visible
    short8 af[4], bfr[4];
#pragma unroll
    for (int mt = 0; mt < 4; mt++) af[mt] = *(const short8*)(ar + mt * 16 * 32);
#pragma unroll
    for (int nt = 0; nt < 4; nt++) bfr[nt] = *(const short8*)(br + nt * 16 * 32);
#pragma unroll
    for (int mt = 0; mt < 4; mt++)
#pragma unroll
      for (int nt = 0; nt < 4; nt++)
        acc[mt][nt] = __builtin_amdgcn_mfma_f32_16x16x32_bf16(af[mt], bfr[nt], acc[mt][nt], 0, 0, 0);
    __syncthreads();                        // frags consumed; LDS reusable
  }
}

// rope phase helpers: freq(n) = 2^(-(n&~1)/512) / (2pi); ph = frac(t*freq)
__device__ __forceinline__ void rope_cs(int n, int t, float& c, float& s) {
  float f = exp2f((float)(-(n & ~1)) * (1.0f / 512.0f)) * 0.15915494f;
  float ph = (float)t * f;
  ph -= floorf(ph);
  __sincosf(ph * 6.2831853f, &s, &c);
}

// ---------------------------------------------------------------------------
// EPI: 0 = store f32
//      1 = relu -> rope -> bf16   (encoder GEMM producing QR directly)
//      3 = atomicAdd f32 (split-K)
//      4 = relu(acc) * unrope(C in-place) -> bf16  (xy over QR buffer)
// grid.z = batch*nsplits + split; per-batch strides aB/bB/cB (elements)
// ---------------------------------------------------------------------------
template<int EPI>
__global__ __launch_bounds__(256, 2) void gemm_bt(
    const u16* __restrict__ A, const u16* __restrict__ B, void* __restrict__ C,
    int K, int lda, int ldb, int ldc, int nsplits, long aB, long bB, long cB)
{
  __shared__ __align__(16) u16 As[128 * 32];
  __shared__ __align__(16) u16 Bs[128 * 32];
  int bn = blockIdx.x, bm = blockIdx.y;
  int batch = blockIdx.z / nsplits, sp = blockIdx.z % nsplits;
  int Klen = K / nsplits, kb = sp * Klen;

  f32x4 acc[4][4];
  gemm_core(A + (long)batch * aB, B + (long)batch * bB, lda, ldb, Klen, kb, bm, bn, As, Bs, acc);

  int lane = threadIdx.x & 63, w = threadIdx.x >> 6;
  int wm = (w >> 1) << 6, wn = (w & 1) << 6;
  int lane15 = lane & 15, quad = lane >> 4;

#pragma unroll
  for (int mt = 0; mt < 4; mt++)
#pragma unroll
    for (int nt = 0; nt < 4; nt++) {
      int gn = bn * 128 + wn + nt * 16 + lane15;
#pragma unroll
      for (int r = 0; r < 4; r++) {
        int gm = bm * 128 + wm + mt * 16 + quad * 4 + r;
        float v = acc[mt][nt][r];
        long ci = (long)batch * cB + (long)gm * ldc + gn;
        if (EPI == 0) {
          ((float*)C)[ci] = v;
        } else if (EPI == 1) {
          float rv = fmaxf(v, 0.f);
          float ro = __shfl_xor(rv, 1);
          float c, s; rope_cs(gn, gm, c, s);
          float out = (gn & 1) ? (rv * c + ro * s) : (rv * c - ro * s);
          ((u16*)C)[ci] = f2b(out);
        } else if (EPI == 3) {
          atomicAdd(&((float*)C)[ci], v);
        } else if (EPI == 4) {
          u16* Cp = (u16*)C;
          float q = b2f(Cp[ci]);           // QR value at own location
          float qo = __shfl_xor(q, 1);     // neighbor column (same wave instr)
          float c, s; rope_cs(gn, gm, c, s);
          float xs = (gn & 1) ? (q * c - qo * s) : (q * c + qo * s);   // un-rope
          Cp[ci] = f2b(fmaxf(v, 0.f) * xs);
        }
      }
    }
}

// scores = tril(QR QR^T, -1) -> bf16. Packed lower-triangle grid:
// blockIdx.x in [0,136) -> (bm,bn); blockIdx.y = head. Upper tiles pre-zeroed.
__global__ __launch_bounds__(256, 2) void gemm_scores(
    const u16* __restrict__ QR, u16* __restrict__ S, int T)
{
  __shared__ __align__(16) u16 As[128 * 32];
  __shared__ __align__(16) u16 Bs[128 * 32];
  int t = blockIdx.x;
  int bm = (int)((sqrtf(8.0f * t + 1.0f) - 1.0f) * 0.5f);
  while ((bm + 1) * (bm + 2) / 2 <= t) bm++;
  while (bm * (bm + 1) / 2 > t) bm--;
  int bn = t - bm * (bm + 1) / 2;

  const u16* Q = QR + (long)blockIdx.y * (long)T * 8192;
  u16* Sb = S + (long)blockIdx.y * (long)T * T;

  f32x4 acc[4][4];
  gemm_core(Q, Q, 8192, 8192, 8192, 0, bm, bn, As, Bs, acc);

  int lane = threadIdx.x & 63, w = threadIdx.x >> 6;
  int wm = (w >> 1) << 6, wn = (w & 1) << 6;
  int lane15 = lane & 15, quad = lane >> 4;
#pragma unroll
  for (int mt = 0; mt < 4; mt++)
#pragma unroll
    for (int nt = 0; nt < 4; nt++)
#pragma unroll
      for (int r = 0; r < 4; r++) {
        int gm = bm * 128 + wm + mt * 16 + quad * 4 + r;
        int gn = bn * 128 + wn + nt * 16 + lane15;
        Sb[(long)gm * T + gn] = f2b(gm > gn ? acc[mt][nt][r] : 0.f);
      }
}

// ---------------------------------------------------------------------------
__global__ __launch_bounds__(256) void trans_f32_bf16(
    const float* __restrict__ src, u16* __restrict__ dst, int R, int C)
{
  __shared__ float tile[32][33];
  long off = (long)blockIdx.z * R * C;
  const float* s = src + off;
  u16* d = dst + off;
  int lx = threadIdx.x & 31, ly = threadIdx.x >> 5;
  int c = blockIdx.x * 32 + lx;
#pragma unroll
  for (int p = 0; p < 32; p += 8)
    tile[ly + p][lx] = s[(long)(blockIdx.y * 32 + ly + p) * C + c];
  __syncthreads();
  int rr = blockIdx.y * 32 + lx;
#pragma unroll
  for (int p = 0; p < 32; p += 8)
    d[(long)(blockIdx.x * 32 + ly + p) * R + rr] = f2b(tile[lx][ly + p]);
}

__device__ __forceinline__ float block_sum(float v, float* red) {
#pragma unroll
  for (int o = 32; o > 0; o >>= 1) v += __shfl_down(v, o, 64);
  int lane = threadIdx.x & 63, wid = threadIdx.x >> 6;
  if (lane == 0) red[wid] = v;
  __syncthreads();
  float r = red[0] + red[1] + red[2] + red[3];
  __syncthreads();
  return r;
}

__global__ __launch_bounds__(256) void embed_ln(
    const int* __restrict__ idx, const float* __restrict__ embed,
    float* __restrict__ x, u16* __restrict__ xb, u16* __restrict__ xT, int T)
{
  __shared__ float red[4];
  int t = blockIdx.x, d = threadIdx.x;
  float v = embed[(long)idx[t] * 256 + d];
  float mu = block_sum(v, red) * (1.f / 256.f);
  float c = v - mu;
  float var = block_sum(c * c, red) * (1.f / 256.f);
  float o = c * rsqrtf(var + 1e-5f);
  x[(long)t * 256 + d] = o;
  xb[(long)t * 256 + d] = f2b(o);
  xT[(long)d * T + t] = f2b(o);
}

__global__ __launch_bounds__(256) void row_ln(
    const float* __restrict__ in, u16* __restrict__ out)
{
  __shared__ float red[4];
  long row = blockIdx.x;
  int d = threadIdx.x;
  float v = in[row * 256 + d];
  float mu = block_sum(v, red) * (1.f / 256.f);
  float c = v - mu;
  float var = block_sum(c * c, red) * (1.f / 256.f);
  out[row * 256 + d] = f2b(c * rsqrtf(var + 1e-5f));
}

__global__ __launch_bounds__(256) void resid_ln(
    const float* __restrict__ yMLP, float* __restrict__ x,
    u16* __restrict__ xb, u16* __restrict__ xT, int T)
{
  __shared__ float red[4];
  int t = blockIdx.x, d = threadIdx.x;
  float y = yMLP[(long)t * 256 + d];
  float mu1 = block_sum(y, red) * (1.f / 256.f);
  float c1 = y - mu1;
  float var1 = block_sum(c1 * c1, red) * (1.f / 256.f);
  float l1 = c1 * rsqrtf(var1 + 1e-5f);
  float v = x[(long)t * 256 + d] + l1;
  float mu2 = block_sum(v, red) * (1.f / 256.f);
  float c2 = v - mu2;
  float var2 = block_sum(c2 * c2, red) * (1.f / 256.f);
  float o = c2 * rsqrtf(var2 + 1e-5f);
  x[(long)t * 256 + d] = o;
  xb[(long)t * 256 + d] = f2b(o);
  xT[(long)d * T + t] = f2b(o);
}

// ---------------------------------------------------------------------------
extern "C" void kernel_launch(void* const* d_in, const int* in_sizes, int n_in,
                              void* d_out, int out_size, void* d_ws, size_t ws_size,
                              hipStream_t stream) {
  const int*   idx       = (const int*)d_in[0];
  const float* embed     = (const float*)d_in[1];
  const float* encoder   = (const float*)d_in[2];
  const float* encoder_v = (const float*)d_in[3];
  const float* decoder   = (const float*)d_in[4];
  const float* lm_head   = (const float*)d_in[5];
  const int T = in_sizes[0];                 // 2048
  const int D = 256, NH = 4, Nn = 8192, V = 256;

  char* ws = (char*)d_ws;
  size_t off = 0;
  auto alloc = [&](size_t bytes) -> void* {
    void* p = ws + off; off += (bytes + 255) & ~(size_t)255; return p;
  };
  float* x_f32   = (float*)alloc((size_t)T * D * 4);
  float* yMLP    = (float*)alloc((size_t)T * D * 4);
  float* yKV_f32 = (float*)alloc((size_t)NH * T * D * 4);
  u16* x_b    = (u16*)alloc((size_t)T * D * 2);
  u16* xT     = (u16*)alloc((size_t)T * D * 2);
  u16* yKV_b  = (u16*)alloc((size_t)NH * T * D * 2);
  u16* lmT    = (u16*)alloc((size_t)D * V * 2);
  u16* encT   = (u16*)alloc((size_t)NH * Nn * D * 2);
  u16* encvT  = (u16*)alloc((size_t)NH * Nn * D * 2);
  u16* decT   = (u16*)alloc((size_t)D * NH * Nn * 2);
  // head-batch ladder: pick largest HB in {4,2,1} whose QR+scores fit
  size_t per_head = ((size_t)T * T * 2 + 256) + ((size_t)T * Nn * 2 + 256);
  int HB = 4;
  while (HB > 1 && off + (size_t)HB * per_head > ws_size) HB >>= 1;
  u16* scores = (u16*)alloc((size_t)HB * T * T * 2);
  u16* QRxy   = (u16*)alloc((size_t)HB * T * Nn * 2);
  if (off > ws_size) return;

  // one-time weight prep: transpose to K-major bf16
  trans_f32_bf16<<<dim3(Nn / 32, D / 32, NH), 256, 0, stream>>>(encoder, encT, D, Nn);
  trans_f32_bf16<<<dim3(Nn / 32, D / 32, NH), 256, 0, stream>>>(encoder_v, encvT, D, Nn);
  trans_f32_bf16<<<dim3(D / 32, (NH * Nn) / 32, 1), 256, 0, stream>>>(decoder, decT, NH * Nn, D);
  trans_f32_bf16<<<dim3(V / 32, D / 32, 1), 256, 0, stream>>>(lm_head, lmT, D, V);

  embed_ln<<<T, 256, 0, stream>>>(idx, embed, x_f32, x_b, xT, T);

  for (int l = 0; l < 2; l++) {
    hipMemsetAsync(yMLP, 0, (size_t)T * D * 4, stream);
    for (int h0 = 0; h0 < NH; h0 += HB) {
      // QR = rope(relu(x @ encoder[h]))  (rope fused in epilogue)
      gemm_bt<1><<<dim3(Nn / 128, T / 128, HB), 256, 0, stream>>>(
          x_b, encT + (size_t)h0 * Nn * D, QRxy,
          D, D, D, Nn, 1, 0L, (long)Nn * D, (long)T * Nn);
      // scores = tril(QR QR^T, -1); upper region stays memset-zero
      hipMemsetAsync(scores, 0, (size_t)HB * T * T * 2, stream);
      gemm_scores<<<dim3(136, HB, 1), 256, 0, stream>>>(QRxy, scores, T);
      // yKV = scores @ x (split-K=8, atomic f32)
      hipMemsetAsync(yKV_f32, 0, (size_t)HB * T * D * 4, stream);
      gemm_bt<3><<<dim3(D / 128, T / 128, HB * 8), 256, 0, stream>>>(
          scores, xT, yKV_f32,
          T, T, T, D, 8, (long)T * T, 0L, (long)T * D);
      // yKV = ln(yKV)
      row_ln<<<HB * T, 256, 0, stream>>>(yKV_f32, yKV_b);
      // xy = relu(yKV @ encoder_v[h]) * unrope(QR), in-place over QR
      gemm_bt<4><<<dim3(Nn / 128, T / 128, HB), 256, 0, stream>>>(
          yKV_b, encvT + (size_t)h0 * Nn * D, QRxy,
          D, D, D, Nn, 1, (long)T * D, (long)Nn * D, (long)T * Nn);
      // yMLP += xy @ decoder[h]  (split-K=8, atomic f32)
      gemm_bt<3><<<dim3(D / 128, T / 128, HB * 8), 256, 0, stream>>>(
          QRxy, decT + (size_t)h0 * Nn, yMLP,
          Nn, Nn, NH * Nn, D, 8, (long)T * Nn, (long)Nn, 0L);
    }
    resid_ln<<<T, 256, 0, stream>>>(yMLP, x_f32, x_b, xT, T);
  }

  // logits = x @ lm_head (f32 out)
  gemm_bt<0><<<dim3(V / 128, T / 128, 1), 256, 0, stream>>>(
      x_b, lmT, d_out, D, D, D, V, 1, 0L, 0L, 0L);
}

// Round 4
// 1309.565 us; speedup vs baseline: 1.7016x; 1.0908x over previous
//
#include <hip/hip_runtime.h>
#include <hip/hip_bf16.h>
#include <math.h>

typedef unsigned short u16;
typedef unsigned int u32;
typedef __attribute__((ext_vector_type(8))) short short8;
typedef __attribute__((ext_vector_type(4))) float f32x4;

__device__ __forceinline__ u16 f2b(float f) {
  u32 u = __builtin_bit_cast(u32, f);
  u = (u + 0x7fffu + ((u >> 16) & 1u)) >> 16;   // RNE
  return (u16)u;
}
__device__ __forceinline__ float b2f(u16 s) {
  return __builtin_bit_cast(float, (u32)s << 16);
}

// async global->LDS, 16B per lane; LDS dest = wave-uniform base + lane*16
__device__ __forceinline__ void ld_g2l(const u16* g, u16* l) {
  __builtin_amdgcn_global_load_lds(
      (const __attribute__((address_space(1))) unsigned int*)g,
      (__attribute__((address_space(3))) unsigned int*)l, 16, 0, 0);
}

// ---------------------------------------------------------------------------
// Core 128x128 tile GEMM (256 threads, 4 waves of 64x64), BK=32, pitch-32 LDS.
// ---------------------------------------------------------------------------
__device__ __forceinline__ void gemm_core(
    const u16* __restrict__ A, const u16* __restrict__ B,
    int lda, int ldb, int Klen, int kb, int bm, int bn,
    u16* __restrict__ As, u16* __restrict__ Bs, f32x4 (&acc)[4][4])
{
  int tid = threadIdx.x;
  int w = tid >> 6, lane = tid & 63;
  int srow = (w << 4) + (lane >> 2);       // 0..63
  int scol = (lane & 3) << 3;              // element 0,8,16,24
  const u16* ga0 = A + (long)(bm * 128 + srow) * lda + kb + scol;
  const u16* ga1 = ga0 + (long)64 * lda;
  const u16* gb0 = B + (long)(bn * 128 + srow) * ldb + kb + scol;
  const u16* gb1 = gb0 + (long)64 * ldb;
  u16* la0 = As + (w << 9);  u16* la1 = la0 + 2048;
  u16* lb0 = Bs + (w << 9);  u16* lb1 = lb0 + 2048;

  int wm = (w >> 1) << 6, wn = (w & 1) << 6;
  int lane15 = lane & 15, quad = lane >> 4;
  const u16* ar = As + (wm + lane15) * 32 + quad * 8;
  const u16* br = Bs + (wn + lane15) * 32 + quad * 8;

#pragma unroll
  for (int i = 0; i < 4; i++)
#pragma unroll
    for (int j = 0; j < 4; j++) { f32x4 z = {0.f, 0.f, 0.f, 0.f}; acc[i][j] = z; }

  for (int k = 0; k < Klen; k += 32) {
    ld_g2l(ga0 + k, la0);
    ld_g2l(ga1 + k, la1);
    ld_g2l(gb0 + k, lb0);
    ld_g2l(gb1 + k, lb1);
    __syncthreads();
    short8 af[4], bfr[4];
#pragma unroll
    for (int mt = 0; mt < 4; mt++) af[mt] = *(const short8*)(ar + mt * 16 * 32);
#pragma unroll
    for (int nt = 0; nt < 4; nt++) bfr[nt] = *(const short8*)(br + nt * 16 * 32);
#pragma unroll
    for (int mt = 0; mt < 4; mt++)
#pragma unroll
      for (int nt = 0; nt < 4; nt++)
        acc[mt][nt] = __builtin_amdgcn_mfma_f32_16x16x32_bf16(af[mt], bfr[nt], acc[mt][nt], 0, 0, 0);
    __syncthreads();
  }
}

// rope phase: freq(n) = 2^(-(n&~1)/512) / (2pi); ph = frac(t*freq)
__device__ __forceinline__ void rope_cs(int n, int t, float& c, float& s) {
  float f = exp2f((float)(-(n & ~1)) * (1.0f / 512.0f)) * 0.15915494f;
  float ph = (float)t * f;
  ph -= floorf(ph);
  __sincosf(ph * 6.2831853f, &s, &c);
}

// ---------------------------------------------------------------------------
// EPI: 0 = store f32
//      1 = relu -> rope -> bf16   (encoder GEMM producing QR directly)
//      3 = atomicAdd f32 (split-K)
//      4 = relu(acc) * unrope(C in-place) -> bf16  (xy over QR buffer)
// tri=1: A is strictly-lower-triangular -> clamp K at (bm+1)*128
// ---------------------------------------------------------------------------
template<int EPI>
__global__ __launch_bounds__(256, 2) void gemm_bt(
    const u16* __restrict__ A, const u16* __restrict__ B, void* __restrict__ C,
    int K, int lda, int ldb, int ldc, int nsplits, long aB, long bB, long cB,
    int tri)
{
  __shared__ __align__(16) u16 As[128 * 32];
  __shared__ __align__(16) u16 Bs[128 * 32];
  int bn = blockIdx.x, bm = blockIdx.y;
  int batch = blockIdx.z / nsplits, sp = blockIdx.z % nsplits;
  int Klen = K / nsplits, kb = sp * Klen;
  if (tri) {
    int kend = (bm + 1) * 128;               // A cols >= kend are all zero
    if (kb >= kend) return;                  // nothing to add (EPI==3 path)
    if (kb + Klen > kend) Klen = kend - kb;  // multiple of 32 by construction
  }

  f32x4 acc[4][4];
  gemm_core(A + (long)batch * aB, B + (long)batch * bB, lda, ldb, Klen, kb, bm, bn, As, Bs, acc);

  int lane = threadIdx.x & 63, w = threadIdx.x >> 6;
  int wm = (w >> 1) << 6, wn = (w & 1) << 6;
  int lane15 = lane & 15, quad = lane >> 4;

#pragma unroll
  for (int mt = 0; mt < 4; mt++)
#pragma unroll
    for (int nt = 0; nt < 4; nt++) {
      int gn = bn * 128 + wn + nt * 16 + lane15;
#pragma unroll
      for (int r = 0; r < 4; r++) {
        int gm = bm * 128 + wm + mt * 16 + quad * 4 + r;
        float v = acc[mt][nt][r];
        long ci = (long)batch * cB + (long)gm * ldc + gn;
        if (EPI == 0) {
          ((float*)C)[ci] = v;
        } else if (EPI == 1) {
          float rv = fmaxf(v, 0.f);
          float ro = __shfl_xor(rv, 1);
          float c, s; rope_cs(gn, gm, c, s);
          float out = (gn & 1) ? (rv * c + ro * s) : (rv * c - ro * s);
          ((u16*)C)[ci] = f2b(out);
        } else if (EPI == 3) {
          atomicAdd(&((float*)C)[ci], v);
        } else if (EPI == 4) {
          u16* Cp = (u16*)C;
          float q = b2f(Cp[ci]);
          float qo = __shfl_xor(q, 1);
          float c, s; rope_cs(gn, gm, c, s);
          float xs = (gn & 1) ? (q * c - qo * s) : (q * c + qo * s);   // un-rope
          Cp[ci] = f2b(fmaxf(v, 0.f) * xs);
        }
      }
    }
}

// ---------------------------------------------------------------------------
// scores = tril(QR QR^T, -1) -> bf16. 512 threads / 8 waves:
// wave w: quadrant q=w&3 (64x64), K-half = w>>2 (even/odd 32-chunks of BK=64).
// Per wave per BK=64: 4 ld_g2l + 8 ds_read_b128 + 16 MFMA (m97 ratio, half
// the barriers, 2x waves/CU vs 256-thr version). Cross-half LDS reduction at
// end. Upper tiles (bn>bm) zero-fill and exit (replaces scores memset).
// ---------------------------------------------------------------------------
__global__ __launch_bounds__(512, 2) void gemm_scores(
    const u16* __restrict__ QR, u16* __restrict__ S, int T)
{
  __shared__ __align__(16) u16 lds[4][128 * 32];   // A0, A1, B0, B1 (8KB each)
  int bn = blockIdx.x, bm = blockIdx.y;
  u16* Sb = S + (long)blockIdx.z * (long)T * T;
  int tid = threadIdx.x;

  if (bn > bm) {                       // strictly above diagonal: zero tile
    for (int i = tid; i < 128 * 128 / 8; i += 512) {
      int r = i >> 4, c8 = (i & 15) << 3;
      *(uint4*)(&Sb[(long)(bm * 128 + r) * T + bn * 128 + c8]) = make_uint4(0u, 0u, 0u, 0u);
    }
    return;
  }

  const u16* Q = QR + (long)blockIdx.z * (long)T * 8192;
  int w = tid >> 6, lane = tid & 63;
  int srow = (w << 4) + (lane >> 2);   // 0..127 across 8 waves
  int scol = (lane & 3) << 3;
  const u16* ga = Q + (long)(bm * 128 + srow) * 8192 + scol;
  const u16* gb = Q + (long)(bn * 128 + srow) * 8192 + scol;
  u16* lA0 = lds[0] + (w << 9);
  u16* lA1 = lds[1] + (w << 9);
  u16* lB0 = lds[2] + (w << 9);
  u16* lB1 = lds[3] + (w << 9);

  int q = w & 3, half = w >> 2;
  int wm = (q >> 1) << 6, wn = (q & 1) << 6;
  int lane15 = lane & 15, quad = lane >> 4;
  const u16* ar = lds[half] + (wm + lane15) * 32 + quad * 8;
  const u16* br = lds[2 + half] + (wn + lane15) * 32 + quad * 8;

  f32x4 acc[4][4];
#pragma unroll
  for (int i = 0; i < 4; i++)
#pragma unroll
    for (int j = 0; j < 4; j++) { f32x4 z = {0.f, 0.f, 0.f, 0.f}; acc[i][j] = z; }

  for (int k = 0; k < 8192; k += 64) {
    ld_g2l(ga + k, lA0);
    ld_g2l(ga + k + 32, lA1);
    ld_g2l(gb + k, lB0);
    ld_g2l(gb + k + 32, lB1);
    __syncthreads();
    short8 af[4], bfr[4];
#pragma unroll
    for (int mt = 0; mt < 4; mt++) af[mt] = *(const short8*)(ar + mt * 16 * 32);
#pragma unroll
    for (int nt = 0; nt < 4; nt++) bfr[nt] = *(const short8*)(br + nt * 16 * 32);
#pragma unroll
    for (int mt = 0; mt < 4; mt++)
#pragma unroll
      for (int nt = 0; nt < 4; nt++)
        acc[mt][nt] = __builtin_amdgcn_mfma_f32_16x16x32_bf16(af[mt], bfr[nt], acc[mt][nt], 0, 0, 0);
    __syncthreads();
  }

  // reduce K-halves: pairs (0,4),(1,5) in round 0; (2,6),(3,7) in round 1
  float* red = (float*)&lds[0][0];     // 32KB = 2 waves x 64 lanes x 64 floats
#pragma unroll
  for (int round = 0; round < 2; round++) {
    if (half == 1 && (q >> 1) == round) {
      float* dst = red + ((q & 1) * 64 + lane) * 64;
#pragma unroll
      for (int i = 0; i < 4; i++)
#pragma unroll
        for (int j = 0; j < 4; j++) *(f32x4*)(dst + (i * 4 + j) * 4) = acc[i][j];
    }
    __syncthreads();
    if (half == 0 && (q >> 1) == round) {
      float* src = red + ((q & 1) * 64 + lane) * 64;
#pragma unroll
      for (int i = 0; i < 4; i++)
#pragma unroll
        for (int j = 0; j < 4; j++) {
          f32x4 t = *(f32x4*)(src + (i * 4 + j) * 4);
          acc[i][j] += t;
        }
    }
    __syncthreads();
  }

  if (half == 0) {
#pragma unroll
    for (int mt = 0; mt < 4; mt++)
#pragma unroll
      for (int nt = 0; nt < 4; nt++)
#pragma unroll
        for (int r = 0; r < 4; r++) {
          int gm = bm * 128 + wm + mt * 16 + quad * 4 + r;
          int gn = bn * 128 + wn + nt * 16 + lane15;
          Sb[(long)gm * T + gn] = f2b(gm > gn ? acc[mt][nt][r] : 0.f);
        }
  }
}

// ---------------------------------------------------------------------------
__global__ __launch_bounds__(256) void trans_f32_bf16(
    const float* __restrict__ src, u16* __restrict__ dst, int R, int C)
{
  __shared__ float tile[32][33];
  long off = (long)blockIdx.z * R * C;
  const float* s = src + off;
  u16* d = dst + off;
  int lx = threadIdx.x & 31, ly = threadIdx.x >> 5;
  int c = blockIdx.x * 32 + lx;
#pragma unroll
  for (int p = 0; p < 32; p += 8)
    tile[ly + p][lx] = s[(long)(blockIdx.y * 32 + ly + p) * C + c];
  __syncthreads();
  int rr = blockIdx.y * 32 + lx;
#pragma unroll
  for (int p = 0; p < 32; p += 8)
    d[(long)(blockIdx.x * 32 + ly + p) * R + rr] = f2b(tile[lx][ly + p]);
}

__device__ __forceinline__ float block_sum(float v, float* red) {
#pragma unroll
  for (int o = 32; o > 0; o >>= 1) v += __shfl_down(v, o, 64);
  int lane = threadIdx.x & 63, wid = threadIdx.x >> 6;
  if (lane == 0) red[wid] = v;
  __syncthreads();
  float r = red[0] + red[1] + red[2] + red[3];
  __syncthreads();
  return r;
}

__global__ __launch_bounds__(256) void embed_ln(
    const int* __restrict__ idx, const float* __restrict__ embed,
    float* __restrict__ x, u16* __restrict__ xb, u16* __restrict__ xT, int T)
{
  __shared__ float red[4];
  int t = blockIdx.x, d = threadIdx.x;
  float v = embed[(long)idx[t] * 256 + d];
  float mu = block_sum(v, red) * (1.f / 256.f);
  float c = v - mu;
  float var = block_sum(c * c, red) * (1.f / 256.f);
  float o = c * rsqrtf(var + 1e-5f);
  x[(long)t * 256 + d] = o;
  xb[(long)t * 256 + d] = f2b(o);
  xT[(long)d * T + t] = f2b(o);
}

__global__ __launch_bounds__(256) void row_ln(
    const float* __restrict__ in, u16* __restrict__ out)
{
  __shared__ float red[4];
  long row = blockIdx.x;
  int d = threadIdx.x;
  float v = in[row * 256 + d];
  float mu = block_sum(v, red) * (1.f / 256.f);
  float c = v - mu;
  float var = block_sum(c * c, red) * (1.f / 256.f);
  out[row * 256 + d] = f2b(c * rsqrtf(var + 1e-5f));
}

__global__ __launch_bounds__(256) void resid_ln(
    const float* __restrict__ yMLP, float* __restrict__ x,
    u16* __restrict__ xb, u16* __restrict__ xT, int T)
{
  __shared__ float red[4];
  int t = blockIdx.x, d = threadIdx.x;
  float y = yMLP[(long)t * 256 + d];
  float mu1 = block_sum(y, red) * (1.f / 256.f);
  float c1 = y - mu1;
  float var1 = block_sum(c1 * c1, red) * (1.f / 256.f);
  float l1 = c1 * rsqrtf(var1 + 1e-5f);
  float v = x[(long)t * 256 + d] + l1;
  float mu2 = block_sum(v, red) * (1.f / 256.f);
  float c2 = v - mu2;
  float var2 = block_sum(c2 * c2, red) * (1.f / 256.f);
  float o = c2 * rsqrtf(var2 + 1e-5f);
  x[(long)t * 256 + d] = o;
  xb[(long)t * 256 + d] = f2b(o);
  xT[(long)d * T + t] = f2b(o);
}

// ---------------------------------------------------------------------------
extern "C" void kernel_launch(void* const* d_in, const int* in_sizes, int n_in,
                              void* d_out, int out_size, void* d_ws, size_t ws_size,
                              hipStream_t stream) {
  const int*   idx       = (const int*)d_in[0];
  const float* embed     = (const float*)d_in[1];
  const float* encoder   = (const float*)d_in[2];
  const float* encoder_v = (const float*)d_in[3];
  const float* decoder   = (const float*)d_in[4];
  const float* lm_head   = (const float*)d_in[5];
  const int T = in_sizes[0];                 // 2048
  const int D = 256, NH = 4, Nn = 8192, V = 256;

  char* ws = (char*)d_ws;
  size_t off = 0;
  auto alloc = [&](size_t bytes) -> void* {
    void* p = ws + off; off += (bytes + 255) & ~(size_t)255; return p;
  };
  float* x_f32   = (float*)alloc((size_t)T * D * 4);
  float* yMLP    = (float*)alloc((size_t)T * D * 4);
  float* yKV_f32 = (float*)alloc((size_t)NH * T * D * 4);
  u16* x_b    = (u16*)alloc((size_t)T * D * 2);
  u16* xT     = (u16*)alloc((size_t)T * D * 2);
  u16* yKV_b  = (u16*)alloc((size_t)NH * T * D * 2);
  u16* lmT    = (u16*)alloc((size_t)D * V * 2);
  u16* encT   = (u16*)alloc((size_t)NH * Nn * D * 2);
  u16* encvT  = (u16*)alloc((size_t)NH * Nn * D * 2);
  u16* decT   = (u16*)alloc((size_t)D * NH * Nn * 2);
  // head-batch ladder: pick largest HB in {4,2,1} whose QR+scores fit
  size_t per_head = ((size_t)T * T * 2 + 256) + ((size_t)T * Nn * 2 + 256);
  int HB = 4;
  while (HB > 1 && off + (size_t)HB * per_head > ws_size) HB >>= 1;
  u16* scores = (u16*)alloc((size_t)HB * T * T * 2);
  u16* QRxy   = (u16*)alloc((size_t)HB * T * Nn * 2);
  if (off > ws_size) return;

  // one-time weight prep: transpose to K-major bf16
  trans_f32_bf16<<<dim3(Nn / 32, D / 32, NH), 256, 0, stream>>>(encoder, encT, D, Nn);
  trans_f32_bf16<<<dim3(Nn / 32, D / 32, NH), 256, 0, stream>>>(encoder_v, encvT, D, Nn);
  trans_f32_bf16<<<dim3(D / 32, (NH * Nn) / 32, 1), 256, 0, stream>>>(decoder, decT, NH * Nn, D);
  trans_f32_bf16<<<dim3(V / 32, D / 32, 1), 256, 0, stream>>>(lm_head, lmT, D, V);

  embed_ln<<<T, 256, 0, stream>>>(idx, embed, x_f32, x_b, xT, T);

  for (int l = 0; l < 2; l++) {
    hipMemsetAsync(yMLP, 0, (size_t)T * D * 4, stream);
    for (int h0 = 0; h0 < NH; h0 += HB) {
      // QR = rope(relu(x @ encoder[h]))  (rope fused in epilogue)
      gemm_bt<1><<<dim3(Nn / 128, T / 128, HB), 256, 0, stream>>>(
          x_b, encT + (size_t)h0 * Nn * D, QRxy,
          D, D, D, Nn, 1, 0L, (long)Nn * D, (long)T * Nn, 0);
      // scores = tril(QR QR^T, -1); upper tiles zero-filled in-grid
      gemm_scores<<<dim3(T / 128, T / 128, HB), 512, 0, stream>>>(QRxy, scores, T);
      // yKV = scores @ x (split-K=8, atomic f32, triangular K-clamp)
      hipMemsetAsync(yKV_f32, 0, (size_t)HB * T * D * 4, stream);
      gemm_bt<3><<<dim3(D / 128, T / 128, HB * 8), 256, 0, stream>>>(
          scores, xT, yKV_f32,
          T, T, T, D, 8, (long)T * T, 0L, (long)T * D, 1);
      // yKV = ln(yKV)
      row_ln<<<HB * T, 256, 0, stream>>>(yKV_f32, yKV_b);
      // xy = relu(yKV @ encoder_v[h]) * unrope(QR), in-place over QR
      gemm_bt<4><<<dim3(Nn / 128, T / 128, HB), 256, 0, stream>>>(
          yKV_b, encvT + (size_t)h0 * Nn * D, QRxy,
          D, D, D, Nn, 1, (long)T * D, (long)Nn * D, (long)T * Nn, 0);
      // yMLP += xy @ decoder[h]  (split-K=8, atomic f32)
      gemm_bt<3><<<dim3(D / 128, T / 128, HB * 8), 256, 0, stream>>>(
          QRxy, decT + (size_t)h0 * Nn, yMLP,
          Nn, Nn, NH * Nn, D, 8, (long)T * Nn, (long)Nn, 0L, 0);
    }
    resid_ln<<<T, 256, 0, stream>>>(yMLP, x_f32, x_b, xT, T);
  }

  // logits = x @ lm_head (f32 out)
  gemm_bt<0><<<dim3(V / 128, T / 128, 1), 256, 0, stream>>>(
      x_b, lmT, d_out, D, D, D, V, 1, 0L, 0L, 0L, 0);
}